// Round 9
// baseline (385.842 us; speedup 1.0000x reference)
//
#include <hip/hip_runtime.h>

constexpr int B  = 8,  P = 50, N = 128, M = 128;
constexpr int EMB = 128, H = 8, D = 16;
constexpr int NE = 8;
constexpr int HD = H * D;        // 128
constexpr int E1 = EMB + 1;      // 129
constexpr int BP = B * P;        // 400
constexpr int T  = BP * N;       // 51200 tokens

// ---------------------------------------------------------------------------
// K0: We'[e][f] = sum_o We[e][f][o]*Wfinal[o]; b'[e] = be[e].Wfinal.
// ---------------------------------------------------------------------------
__global__ void prep_kernel(const float* __restrict__ We,
                            const float* __restrict__ be,
                            const float* __restrict__ Wf,
                            float* __restrict__ Wep, float* __restrict__ bpv,
                            float* __restrict__ importance) {
    const int e = blockIdx.x;
    const int f = threadIdx.x;

    float a = 0.f;
    const long base = ((long)e * HD + f) * E1;
    for (int o = 0; o < E1; ++o) a += We[base + o] * Wf[o];
    Wep[e * HD + f] = a;

    if (f == 0) {
        float b = 0.f;
        for (int o = 0; o < E1; ++o) b += be[(long)e * E1 + o] * Wf[o];
        bpv[e] = b;
    }
    if (e == 0 && f < NE) importance[f] = 0.f;
}

// ---------------------------------------------------------------------------
// K1: q/k/v projections (r7-proven). grid (400, 3), block 256. 128x128 tile,
// 8x8 acc, K-tile 8, ping-pong LDS, one barrier per tile, reg-staged loads.
// ---------------------------------------------------------------------------
__global__ __launch_bounds__(256) void proj_kernel(
    const float* __restrict__ nodes,  // [T][128]
    const float* __restrict__ routes, // [T][129]
    const float* __restrict__ Wq, const float* __restrict__ Wk,
    const float* __restrict__ Wv,
    float* __restrict__ qo, float* __restrict__ ko, float* __restrict__ vo) {
    const int mat = blockIdx.y;
    const float* __restrict__ X = (mat == 0) ? nodes : routes;
    const float* __restrict__ W = (mat == 0) ? Wq : (mat == 1 ? Wk : Wv);
    float* __restrict__ out     = (mat == 0) ? qo : (mat == 1 ? ko : vo);
    const int Kd = (mat == 0) ? EMB : E1;
    const int nit = (Kd + 7) >> 3;

    const int row0 = blockIdx.x * 128;
    const int tid  = threadIdx.x;
    const int tr   = tid >> 4;        // 0..15
    const int tc   = tid & 15;        // 0..15

    __shared__ float XT[2][8][132];   // [buf][k][row], padded
    __shared__ float WS[2][8][132];   // [buf][k][col]

    float acc[8][8];
    #pragma unroll
    for (int i = 0; i < 8; ++i)
        #pragma unroll
        for (int j = 0; j < 8; ++j) acc[i][j] = 0.f;

    float xr[4];
    float4 wr;
    const int xkx = tid & 7, xrr = tid >> 3;          // +i*32 rows
    const int wkx = tid >> 5, wc4 = (tid & 31) * 4;

    {   // prologue: fetch tile 0
        #pragma unroll
        for (int i = 0; i < 4; ++i) {
            int kg = xkx;
            xr[i] = (kg < Kd) ? X[(long)(row0 + xrr + i * 32) * Kd + kg] : 0.f;
        }
        wr = (wkx < Kd) ? *(const float4*)&W[(long)wkx * HD + wc4]
                        : make_float4(0.f, 0.f, 0.f, 0.f);
        #pragma unroll
        for (int i = 0; i < 4; ++i) XT[0][xkx][xrr + i * 32] = xr[i];
        *(float4*)&WS[0][wkx][wc4] = wr;
    }
    __syncthreads();

    for (int it = 0; it < nit; ++it) {
        const int buf = it & 1;
        if (it + 1 < nit) {
            const int kk = (it + 1) * 8;
            #pragma unroll
            for (int i = 0; i < 4; ++i) {
                int kg = kk + xkx;
                xr[i] = (kg < Kd) ? X[(long)(row0 + xrr + i * 32) * Kd + kg] : 0.f;
            }
            int kg = kk + wkx;
            wr = (kg < Kd) ? *(const float4*)&W[(long)kg * HD + wc4]
                           : make_float4(0.f, 0.f, 0.f, 0.f);
        }

        #pragma unroll
        for (int k = 0; k < 8; ++k) {
            float4 xa = *(const float4*)&XT[buf][k][tr * 4];
            float4 xb = *(const float4*)&XT[buf][k][64 + tr * 4];
            float4 wa = *(const float4*)&WS[buf][k][tc * 4];
            float4 wb = *(const float4*)&WS[buf][k][64 + tc * 4];
            float xv[8] = {xa.x, xa.y, xa.z, xa.w, xb.x, xb.y, xb.z, xb.w};
            float wvv[8] = {wa.x, wa.y, wa.z, wa.w, wb.x, wb.y, wb.z, wb.w};
            #pragma unroll
            for (int i = 0; i < 8; ++i)
                #pragma unroll
                for (int j = 0; j < 8; ++j) acc[i][j] += xv[i] * wvv[j];
        }

        if (it + 1 < nit) {
            const int nb = buf ^ 1;
            #pragma unroll
            for (int i = 0; i < 4; ++i) XT[nb][xkx][xrr + i * 32] = xr[i];
            *(float4*)&WS[nb][wkx][wc4] = wr;
        }
        __syncthreads();
    }

    #pragma unroll
    for (int i = 0; i < 8; ++i) {
        int r = row0 + (i < 4 ? 0 : 64) + tr * 4 + (i & 3);
        float4 o0 = make_float4(acc[i][0], acc[i][1], acc[i][2], acc[i][3]);
        float4 o1 = make_float4(acc[i][4], acc[i][5], acc[i][6], acc[i][7]);
        *(float4*)&out[(long)r * HD + tc * 4]      = o0;
        *(float4*)&out[(long)r * HD + 64 + tc * 4] = o1;
    }
}

// ---------------------------------------------------------------------------
// K2: masked attention per (bp, head). grid (BP, 8), block 64 (1 wave).
// k/v staged in TWO 64-row chunks -> 8 KB LDS (20 waves/CU cap, was 10).
// Same load pattern / serial order as r7 (bit-identical). Barriers in a
// 1-wave block are just waitcnts. Grid (BP,H): all 8 heads of a bp map to
// the same XCD (400%8==0) -> rmask L2 reuse (r8 confirmed the inverse).
// ---------------------------------------------------------------------------
__global__ __launch_bounds__(64) void attn_kernel(
    const float* __restrict__ qbuf,   // [T][128]
    const float* __restrict__ kbuf,   // [T][128]
    const float* __restrict__ vbuf,   // [T][128]
    const float* __restrict__ rmask,  // [BP*N][M]
    const float* __restrict__ ninf,   // [BP*N]
    float* __restrict__ xcat) {       // [T][128]
    const int bp  = blockIdx.x;
    const int h   = blockIdx.y;
    const int tid = threadIdx.x;

    __shared__ float kh[64][16];      // 4 KB
    __shared__ float vh[64][16];      // 4 KB

    const long t0 = (long)bp * N + tid, t1 = t0 + 64;

    // q rows, 1/sqrt(D)=0.25 folded in
    float qr0[16], qr1[16];
    {
        const float4* q0 = (const float4*)&qbuf[t0 * HD + h * D];
        const float4* q1 = (const float4*)&qbuf[t1 * HD + h * D];
        #pragma unroll
        for (int i = 0; i < 4; ++i) {
            float4 a = q0[i], b = q1[i];
            qr0[i*4+0] = a.x*0.25f; qr0[i*4+1] = a.y*0.25f;
            qr0[i*4+2] = a.z*0.25f; qr0[i*4+3] = a.w*0.25f;
            qr1[i*4+0] = b.x*0.25f; qr1[i*4+1] = b.y*0.25f;
            qr1[i*4+2] = b.z*0.25f; qr1[i*4+3] = b.w*0.25f;
        }
    }

    const float4* rm0 = (const float4*)&rmask[t0 * M];
    const float4* rm1 = (const float4*)&rmask[t1 * M];

    float sum0 = 0.f, sum1 = 0.f;
    float o0[16], o1[16];
    #pragma unroll
    for (int d = 0; d < 16; ++d) { o0[d] = 0.f; o1[d] = 0.f; }

    for (int c = 0; c < 2; ++c) {
        // stage rows c*64 .. c*64+63 (same pattern as r7, conflicts 0)
        #pragma unroll
        for (int i = 0; i < 4; ++i) {
            int e = tid + i * 64;          // f4 index, 256 per tensor
            int r = e >> 2, c4 = (e & 3) * 4;
            long grow = (long)bp * M + c * 64 + r;
            *(float4*)&kh[r][c4] = *(const float4*)&kbuf[grow * HD + h * D + c4];
            *(float4*)&vh[r][c4] = *(const float4*)&vbuf[grow * HD + h * D + c4];
        }
        __syncthreads();                   // 1-wave block: waitcnt only

        #pragma unroll
        for (int mbl = 0; mbl < 16; ++mbl) {
            const int mb = c * 16 + mbl;   // global f4-row of rmask
            float4 r0 = rm0[mb], r1 = rm1[mb];
            float r0v[4] = {r0.x, r0.y, r0.z, r0.w};
            float r1v[4] = {r1.x, r1.y, r1.z, r1.w};
            #pragma unroll
            for (int j = 0; j < 4; ++j) {
                const int ml = mbl * 4 + j;        // 0..63 within chunk
                const float4* k4 = (const float4*)&kh[ml][0];
                const float4* v4 = (const float4*)&vh[ml][0];
                float s0 = 0.f, s1 = 0.f;
                #pragma unroll
                for (int q4 = 0; q4 < 4; ++q4) {
                    float4 kq = k4[q4];
                    s0 += qr0[q4*4+0]*kq.x + qr0[q4*4+1]*kq.y
                        + qr0[q4*4+2]*kq.z + qr0[q4*4+3]*kq.w;
                    s1 += qr1[q4*4+0]*kq.x + qr1[q4*4+1]*kq.y
                        + qr1[q4*4+2]*kq.z + qr1[q4*4+3]*kq.w;
                }
                float e0 = __expf(s0 + r0v[j]);
                float e1 = __expf(s1 + r1v[j]);
                sum0 += e0; sum1 += e1;
                #pragma unroll
                for (int q4 = 0; q4 < 4; ++q4) {
                    float4 vq = v4[q4];
                    o0[q4*4+0] += e0*vq.x; o0[q4*4+1] += e0*vq.y;
                    o0[q4*4+2] += e0*vq.z; o0[q4*4+3] += e0*vq.w;
                    o1[q4*4+0] += e1*vq.x; o1[q4*4+1] += e1*vq.y;
                    o1[q4*4+2] += e1*vq.z; o1[q4*4+3] += e1*vq.w;
                }
            }
        }
        __syncthreads();
    }

    const float inv0 = ((ninf[t0] == 0.f) ? 1.f : 0.f) / sum0;
    const float inv1 = ((ninf[t1] == 0.f) ? 1.f : 0.f) / sum1;
    #pragma unroll
    for (int q4 = 0; q4 < 4; ++q4) {
        float4 w0 = make_float4(o0[q4*4+0]*inv0, o0[q4*4+1]*inv0,
                                o0[q4*4+2]*inv0, o0[q4*4+3]*inv0);
        float4 w1 = make_float4(o1[q4*4+0]*inv1, o1[q4*4+1]*inv1,
                                o1[q4*4+2]*inv1, o1[q4*4+3]*inv1);
        *(float4*)&xcat[t0 * HD + h * D + q4 * 4] = w0;
        *(float4*)&xcat[t1 * HD + h * D + q4 * 4] = w1;
    }
}

// ---------------------------------------------------------------------------
// K3a: per-token gating (top-2) + collapsed expert score + 10*tanh.
// grid 200, block 256 (one thread per token; 200*256 == T).
// Same serial f-order as the r5-proven fused kernel -> bit-identical s.
// ---------------------------------------------------------------------------
__global__ __launch_bounds__(256) void gate_kernel(
    const float* __restrict__ xcat, const float* __restrict__ Wg,
    const float* __restrict__ Wep, const float* __restrict__ bpv,
    float* __restrict__ importance, float* __restrict__ sbuf) {
    __shared__ float WgS[EMB][NE];   // 4 KB
    __shared__ float WeS[NE][132];   // padded
    __shared__ float impS[NE];

    const int tid = threadIdx.x;

    {   // WgS: 1024 floats = 256 f4
        int r = tid >> 1, c4 = (tid & 1) * 4;
        *(float4*)&WgS[r][c4] = *(const float4*)&Wg[(long)r * NE + c4];
    }
    {   // WeS: 1024 floats
        int r = tid >> 5, c = (tid & 31) * 4;
        *(float4*)&WeS[r][c] = *(const float4*)&Wep[(long)r * HD + c];
    }
    if (tid < NE) impS[tid] = 0.f;
    __syncthreads();

    const long t = (long)blockIdx.x * 256 + tid;
    const float4* row4 = (const float4*)&xcat[t * HD];

    float gl[NE];
    #pragma unroll
    for (int e = 0; e < NE; ++e) gl[e] = 0.f;
    for (int fb = 0; fb < 32; ++fb) {
        float4 xv = row4[fb];
        float x4[4] = {xv.x, xv.y, xv.z, xv.w};
        #pragma unroll
        for (int j = 0; j < 4; ++j)
            #pragma unroll
            for (int e = 0; e < NE; ++e) gl[e] += x4[j] * WgS[fb * 4 + j][e];
    }

    int e0 = 0; float v0 = gl[0];
    #pragma unroll
    for (int e = 1; e < NE; ++e) if (gl[e] > v0) { v0 = gl[e]; e0 = e; }
    int e1 = -1; float v1 = -3.4e38f;
    #pragma unroll
    for (int e = 0; e < NE; ++e) if (e != e0 && gl[e] > v1) { v1 = gl[e]; e1 = e; }
    float ex = __expf(v1 - v0);
    float g0 = 1.f / (1.f + ex);
    float g1 = ex / (1.f + ex);

    atomicAdd(&impS[e0], g0);
    atomicAdd(&impS[e1], g1);

    float s = g0 * bpv[e0] + g1 * bpv[e1];
    for (int fb = 0; fb < 32; ++fb) {
        float4 xv = row4[fb];
        float x4[4] = {xv.x, xv.y, xv.z, xv.w};
        #pragma unroll
        for (int j = 0; j < 4; ++j) {
            int f = fb * 4 + j;
            s += x4[j] * (g0 * WeS[e0][f] + g1 * WeS[e1][f]);
        }
    }
    sbuf[t] = 10.f * tanhf(s);

    __syncthreads();
    if (tid < NE) atomicAdd(&importance[tid], impS[tid]);
}

// ---------------------------------------------------------------------------
// K3b: softmax over the 128 tokens of each (b,p). grid BP, block 128.
// ---------------------------------------------------------------------------
__global__ __launch_bounds__(128) void softmax_kernel(
    const float* __restrict__ sbuf, const float* __restrict__ ninf,
    float* __restrict__ out) {
    __shared__ float red[N];
    const int bp = blockIdx.x;
    const int n  = threadIdx.x;
    const long t = (long)bp * N + n;

    float s = sbuf[t] + ninf[t];
    red[n] = s;
    __syncthreads();
    for (int off = 64; off > 0; off >>= 1) {
        if (n < off) red[n] = fmaxf(red[n], red[n + off]);
        __syncthreads();
    }
    float mx = red[0];
    __syncthreads();
    float e = __expf(s - mx);
    red[n] = e;
    __syncthreads();
    for (int off = 64; off > 0; off >>= 1) {
        if (n < off) red[n] += red[n + off];
        __syncthreads();
    }
    out[t] = e / red[0];
}

// ---------------------------------------------------------------------------
// K4: moe_loss from importance (f32 at out[T]).
// ---------------------------------------------------------------------------
__global__ void loss_kernel(const float* __restrict__ importance,
                            float* __restrict__ out) {
    if (threadIdx.x == 0) {
        float mean = 0.f;
        #pragma unroll
        for (int e = 0; e < NE; ++e) mean += importance[e];
        mean *= (1.f / NE);
        float var = 0.f;
        #pragma unroll
        for (int e = 0; e < NE; ++e) {
            float d = importance[e] - mean;
            var += d * d;
        }
        var *= (1.f / NE);
        out[T] = var / (mean * mean + 1e-10f);
    }
}

// ---------------------------------------------------------------------------
extern "C" void kernel_launch(void* const* d_in, const int* in_sizes, int n_in,
                              void* d_out, int out_size, void* d_ws, size_t ws_size,
                              hipStream_t stream) {
    const float* nodes  = (const float*)d_in[0];
    const float* routes = (const float*)d_in[1];
    const float* ninf   = (const float*)d_in[2];
    const float* rmask  = (const float*)d_in[3];
    const float* Wq     = (const float*)d_in[4];
    const float* Wk     = (const float*)d_in[5];
    const float* Wv     = (const float*)d_in[6];
    const float* Wg     = (const float*)d_in[7];
    const float* We     = (const float*)d_in[8];
    const float* be     = (const float*)d_in[9];
    const float* Wfin   = (const float*)d_in[10];

    float* ws = (float*)d_ws;
    float* Wep        = ws + 16;
    float* bpv        = ws + 1040;
    float* importance = ws + 1048;
    float* qbuf       = ws + 4096;
    float* kbuf       = qbuf + (long)T * HD;
    float* vbuf       = kbuf + (long)T * HD;
    float* xcat       = vbuf + (long)T * HD;
    float* sbuf       = xcat + (long)T * HD;

    float* out = (float*)d_out;

    prep_kernel<<<NE, 128, 0, stream>>>(We, be, Wfin, Wep, bpv, importance);
    proj_kernel<<<dim3(400, 3), 256, 0, stream>>>(nodes, routes, Wq, Wk, Wv,
                                                  qbuf, kbuf, vbuf);
    attn_kernel<<<dim3(BP, H), 64, 0, stream>>>(qbuf, kbuf, vbuf,
                                                rmask, ninf, xcat);
    gate_kernel<<<200, 256, 0, stream>>>(xcat, Wg, Wep, bpv, importance, sbuf);
    softmax_kernel<<<BP, 128, 0, stream>>>(sbuf, ninf, out);
    loss_kernel<<<1, 64, 0, stream>>>(importance, out);
}

// Round 10
// 307.070 us; speedup vs baseline: 1.2565x; 1.2565x over previous
//
#include <hip/hip_runtime.h>

constexpr int B  = 8,  P = 50, N = 128, M = 128;
constexpr int EMB = 128, H = 8, D = 16;
constexpr int NE = 8;
constexpr int HD = H * D;        // 128
constexpr int E1 = EMB + 1;      // 129
constexpr int BP = B * P;        // 400
constexpr int T  = BP * N;       // 51200 tokens

// ---------------------------------------------------------------------------
// K0: We'[e][f] = sum_o We[e][f][o]*Wfinal[o]; b'[e] = be[e].Wfinal.
// ---------------------------------------------------------------------------
__global__ void prep_kernel(const float* __restrict__ We,
                            const float* __restrict__ be,
                            const float* __restrict__ Wf,
                            float* __restrict__ Wep, float* __restrict__ bpv,
                            float* __restrict__ importance) {
    const int e = blockIdx.x;
    const int f = threadIdx.x;

    float a = 0.f;
    const long base = ((long)e * HD + f) * E1;
    for (int o = 0; o < E1; ++o) a += We[base + o] * Wf[o];
    Wep[e * HD + f] = a;

    if (f == 0) {
        float b = 0.f;
        for (int o = 0; o < E1; ++o) b += be[(long)e * E1 + o] * Wf[o];
        bpv[e] = b;
    }
    if (e == 0 && f < NE) importance[f] = 0.f;
}

// ---------------------------------------------------------------------------
// K1: q/k/v projections (r7-proven). grid (400, 3), block 256. 128x128 tile,
// 8x8 acc, K-tile 8, ping-pong LDS, one barrier per tile, reg-staged loads.
// ---------------------------------------------------------------------------
__global__ __launch_bounds__(256) void proj_kernel(
    const float* __restrict__ nodes,  // [T][128]
    const float* __restrict__ routes, // [T][129]
    const float* __restrict__ Wq, const float* __restrict__ Wk,
    const float* __restrict__ Wv,
    float* __restrict__ qo, float* __restrict__ ko, float* __restrict__ vo) {
    const int mat = blockIdx.y;
    const float* __restrict__ X = (mat == 0) ? nodes : routes;
    const float* __restrict__ W = (mat == 0) ? Wq : (mat == 1 ? Wk : Wv);
    float* __restrict__ out     = (mat == 0) ? qo : (mat == 1 ? ko : vo);
    const int Kd = (mat == 0) ? EMB : E1;
    const int nit = (Kd + 7) >> 3;

    const int row0 = blockIdx.x * 128;
    const int tid  = threadIdx.x;
    const int tr   = tid >> 4;        // 0..15
    const int tc   = tid & 15;        // 0..15

    __shared__ float XT[2][8][132];   // [buf][k][row], padded
    __shared__ float WS[2][8][132];   // [buf][k][col]

    float acc[8][8];
    #pragma unroll
    for (int i = 0; i < 8; ++i)
        #pragma unroll
        for (int j = 0; j < 8; ++j) acc[i][j] = 0.f;

    float xr[4];
    float4 wr;
    const int xkx = tid & 7, xrr = tid >> 3;          // +i*32 rows
    const int wkx = tid >> 5, wc4 = (tid & 31) * 4;

    {   // prologue: fetch tile 0
        #pragma unroll
        for (int i = 0; i < 4; ++i) {
            int kg = xkx;
            xr[i] = (kg < Kd) ? X[(long)(row0 + xrr + i * 32) * Kd + kg] : 0.f;
        }
        wr = (wkx < Kd) ? *(const float4*)&W[(long)wkx * HD + wc4]
                        : make_float4(0.f, 0.f, 0.f, 0.f);
        #pragma unroll
        for (int i = 0; i < 4; ++i) XT[0][xkx][xrr + i * 32] = xr[i];
        *(float4*)&WS[0][wkx][wc4] = wr;
    }
    __syncthreads();

    for (int it = 0; it < nit; ++it) {
        const int buf = it & 1;
        if (it + 1 < nit) {
            const int kk = (it + 1) * 8;
            #pragma unroll
            for (int i = 0; i < 4; ++i) {
                int kg = kk + xkx;
                xr[i] = (kg < Kd) ? X[(long)(row0 + xrr + i * 32) * Kd + kg] : 0.f;
            }
            int kg = kk + wkx;
            wr = (kg < Kd) ? *(const float4*)&W[(long)kg * HD + wc4]
                           : make_float4(0.f, 0.f, 0.f, 0.f);
        }

        #pragma unroll
        for (int k = 0; k < 8; ++k) {
            float4 xa = *(const float4*)&XT[buf][k][tr * 4];
            float4 xb = *(const float4*)&XT[buf][k][64 + tr * 4];
            float4 wa = *(const float4*)&WS[buf][k][tc * 4];
            float4 wb = *(const float4*)&WS[buf][k][64 + tc * 4];
            float xv[8] = {xa.x, xa.y, xa.z, xa.w, xb.x, xb.y, xb.z, xb.w};
            float wvv[8] = {wa.x, wa.y, wa.z, wa.w, wb.x, wb.y, wb.z, wb.w};
            #pragma unroll
            for (int i = 0; i < 8; ++i)
                #pragma unroll
                for (int j = 0; j < 8; ++j) acc[i][j] += xv[i] * wvv[j];
        }

        if (it + 1 < nit) {
            const int nb = buf ^ 1;
            #pragma unroll
            for (int i = 0; i < 4; ++i) XT[nb][xkx][xrr + i * 32] = xr[i];
            *(float4*)&WS[nb][wkx][wc4] = wr;
        }
        __syncthreads();
    }

    #pragma unroll
    for (int i = 0; i < 8; ++i) {
        int r = row0 + (i < 4 ? 0 : 64) + tr * 4 + (i & 3);
        float4 o0 = make_float4(acc[i][0], acc[i][1], acc[i][2], acc[i][3]);
        float4 o1 = make_float4(acc[i][4], acc[i][5], acc[i][6], acc[i][7]);
        *(float4*)&out[(long)r * HD + tc * 4]      = o0;
        *(float4*)&out[(long)r * HD + 64 + tc * 4] = o1;
    }
}

// ---------------------------------------------------------------------------
// K2: masked attention per (bp, head). grid (BP, 8), block 128 = 2 waves.
// Wave w stages AND reads only k/v rows [w*64, w*64+64) -> no staging
// barrier (within-wave lgkmcnt ordering suffices). Each wave runs the
// r7-proven inner body (m-loop NOT force-unrolled -> ~70 VGPR) over its
// 64 m. Partials combined via LDS in canonical low+high order.
// 16 KB LDS per 2 waves -> 20 waves/CU cap (r7: 10).
// ---------------------------------------------------------------------------
__global__ __launch_bounds__(128) void attn_kernel(
    const float* __restrict__ qbuf,   // [T][128]
    const float* __restrict__ kbuf,   // [T][128]
    const float* __restrict__ vbuf,   // [T][128]
    const float* __restrict__ rmask,  // [BP*N][M]
    const float* __restrict__ ninf,   // [BP*N]
    float* __restrict__ xcat) {       // [T][128]
    const int bp   = blockIdx.x;
    const int h    = blockIdx.y;
    const int tid  = threadIdx.x;
    const int w    = tid >> 6;        // wave: m-range half
    const int lane = tid & 63;

    __shared__ float kh[2][64][16];   // 8 KB (half per wave)
    __shared__ float vh[2][64][16];   // 8 KB

    // stage this wave's 64 k/v rows (conflict-free: addr = lane*4 per iter)
    #pragma unroll
    for (int i = 0; i < 4; ++i) {
        int e = lane + i * 64;        // f4 index 0..255
        int r = e >> 2, c4 = (e & 3) * 4;
        long grow = (long)bp * M + w * 64 + r;
        *(float4*)&kh[w][r][c4] = *(const float4*)&kbuf[grow * HD + h * D + c4];
        *(float4*)&vh[w][r][c4] = *(const float4*)&vbuf[grow * HD + h * D + c4];
    }

    const long t0 = (long)bp * N + lane, t1 = t0 + 64;

    // q rows, 1/sqrt(D)=0.25 folded in
    float qr0[16], qr1[16];
    {
        const float4* q0 = (const float4*)&qbuf[t0 * HD + h * D];
        const float4* q1 = (const float4*)&qbuf[t1 * HD + h * D];
        #pragma unroll
        for (int i = 0; i < 4; ++i) {
            float4 a = q0[i], b = q1[i];
            qr0[i*4+0] = a.x*0.25f; qr0[i*4+1] = a.y*0.25f;
            qr0[i*4+2] = a.z*0.25f; qr0[i*4+3] = a.w*0.25f;
            qr1[i*4+0] = b.x*0.25f; qr1[i*4+1] = b.y*0.25f;
            qr1[i*4+2] = b.z*0.25f; qr1[i*4+3] = b.w*0.25f;
        }
    }

    const float4* rm0 = (const float4*)&rmask[t0 * M];
    const float4* rm1 = (const float4*)&rmask[t1 * M];

    float sum0 = 0.f, sum1 = 0.f;
    float o0[16], o1[16];
    #pragma unroll
    for (int d = 0; d < 16; ++d) { o0[d] = 0.f; o1[d] = 0.f; }

    for (int mbl = 0; mbl < 16; ++mbl) {       // NOT force-unrolled (VGPR!)
        const int mb = w * 16 + mbl;           // global f4-row of rmask
        float4 r0 = rm0[mb], r1 = rm1[mb];
        float r0v[4] = {r0.x, r0.y, r0.z, r0.w};
        float r1v[4] = {r1.x, r1.y, r1.z, r1.w};
        #pragma unroll
        for (int j = 0; j < 4; ++j) {
            const int ml = mbl * 4 + j;        // 0..63 within this half
            const float4* k4 = (const float4*)&kh[w][ml][0];
            const float4* v4 = (const float4*)&vh[w][ml][0];
            float s0 = 0.f, s1 = 0.f;
            #pragma unroll
            for (int q4 = 0; q4 < 4; ++q4) {
                float4 kq = k4[q4];
                s0 += qr0[q4*4+0]*kq.x + qr0[q4*4+1]*kq.y
                    + qr0[q4*4+2]*kq.z + qr0[q4*4+3]*kq.w;
                s1 += qr1[q4*4+0]*kq.x + qr1[q4*4+1]*kq.y
                    + qr1[q4*4+2]*kq.z + qr1[q4*4+3]*kq.w;
            }
            float e0 = __expf(s0 + r0v[j]);
            float e1 = __expf(s1 + r1v[j]);
            sum0 += e0; sum1 += e1;
            #pragma unroll
            for (int q4 = 0; q4 < 4; ++q4) {
                float4 vq = v4[q4];
                o0[q4*4+0] += e0*vq.x; o0[q4*4+1] += e0*vq.y;
                o0[q4*4+2] += e0*vq.z; o0[q4*4+3] += e0*vq.w;
                o1[q4*4+0] += e1*vq.x; o1[q4*4+1] += e1*vq.y;
                o1[q4*4+2] += e1*vq.z; o1[q4*4+3] += e1*vq.w;
            }
        }
    }

    // combine wave partials: reuse kh (o0/sum0) and vh (o1/sum1) as [17][64]
    __syncthreads();                  // both waves done reading kh/vh
    float* c0 = &kh[0][0][0];
    float* c1 = &vh[0][0][0];
    if (w == 1) {
        #pragma unroll
        for (int d = 0; d < 16; ++d) {
            c0[d * 64 + lane] = o0[d];
            c1[d * 64 + lane] = o1[d];
        }
        c0[16 * 64 + lane] = sum0;
        c1[16 * 64 + lane] = sum1;
    }
    __syncthreads();
    if (w == 0) {
        #pragma unroll
        for (int d = 0; d < 16; ++d) {
            o0[d] += c0[d * 64 + lane];    // low(m 0..63) + high(m 64..127)
            o1[d] += c1[d * 64 + lane];
        }
        sum0 += c0[16 * 64 + lane];
        sum1 += c1[16 * 64 + lane];

        const float inv0 = ((ninf[t0] == 0.f) ? 1.f : 0.f) / sum0;
        const float inv1 = ((ninf[t1] == 0.f) ? 1.f : 0.f) / sum1;
        #pragma unroll
        for (int q4 = 0; q4 < 4; ++q4) {
            float4 w0 = make_float4(o0[q4*4+0]*inv0, o0[q4*4+1]*inv0,
                                    o0[q4*4+2]*inv0, o0[q4*4+3]*inv0);
            float4 w1 = make_float4(o1[q4*4+0]*inv1, o1[q4*4+1]*inv1,
                                    o1[q4*4+2]*inv1, o1[q4*4+3]*inv1);
            *(float4*)&xcat[t0 * HD + h * D + q4 * 4] = w0;
            *(float4*)&xcat[t1 * HD + h * D + q4 * 4] = w1;
        }
    }
}

// ---------------------------------------------------------------------------
// K3: MoE gating (top-2) + collapsed expert scoring + final softmax.
// grid BP, block 128 (thread = token n). (r5/r7-proven version)
// ---------------------------------------------------------------------------
__global__ __launch_bounds__(128) void moe_final_kernel(
    const float* __restrict__ xcat, const float* __restrict__ Wg,
    const float* __restrict__ ninf, const float* __restrict__ Wep,
    const float* __restrict__ bpv, float* __restrict__ importance,
    float* __restrict__ out) {
    __shared__ float WgS[EMB][NE];   // 4 KB
    __shared__ float WeS[NE][132];   // padded
    __shared__ float red[N];
    __shared__ float impS[NE];

    const int bp = blockIdx.x;
    const int n  = threadIdx.x;

    #pragma unroll
    for (int i = 0; i < 2; ++i) {
        int e = n + i * 128;
        int r = e >> 1, c4 = (e & 1) * 4;
        *(float4*)&WgS[r][c4] = *(const float4*)&Wg[(long)r * NE + c4];
    }
    #pragma unroll
    for (int i = 0; i < 2; ++i) {
        int idx = n + i * 128;
        int r = idx >> 5, c = (idx & 31) * 4;
        *(float4*)&WeS[r][c] = *(const float4*)&Wep[(long)r * HD + c];
    }
    if (n < NE) impS[n] = 0.f;
    __syncthreads();

    const long t = (long)bp * N + n;
    const float4* row4 = (const float4*)&xcat[t * HD];

    float gl[NE];
    #pragma unroll
    for (int e = 0; e < NE; ++e) gl[e] = 0.f;
    for (int fb = 0; fb < 32; ++fb) {
        float4 xv = row4[fb];
        float x4[4] = {xv.x, xv.y, xv.z, xv.w};
        #pragma unroll
        for (int j = 0; j < 4; ++j)
            #pragma unroll
            for (int e = 0; e < NE; ++e) gl[e] += x4[j] * WgS[fb * 4 + j][e];
    }

    int e0 = 0; float v0 = gl[0];
    #pragma unroll
    for (int e = 1; e < NE; ++e) if (gl[e] > v0) { v0 = gl[e]; e0 = e; }
    int e1 = -1; float v1 = -3.4e38f;
    #pragma unroll
    for (int e = 0; e < NE; ++e) if (e != e0 && gl[e] > v1) { v1 = gl[e]; e1 = e; }
    float ex = __expf(v1 - v0);
    float g0 = 1.f / (1.f + ex);
    float g1 = ex / (1.f + ex);

    atomicAdd(&impS[e0], g0);
    atomicAdd(&impS[e1], g1);

    float s = g0 * bpv[e0] + g1 * bpv[e1];
    for (int fb = 0; fb < 32; ++fb) {
        float4 xv = row4[fb];
        float x4[4] = {xv.x, xv.y, xv.z, xv.w};
        #pragma unroll
        for (int j = 0; j < 4; ++j) {
            int f = fb * 4 + j;
            s += x4[j] * (g0 * WeS[e0][f] + g1 * WeS[e1][f]);
        }
    }
    s = 10.f * tanhf(s) + ninf[t];

    red[n] = s;
    __syncthreads();
    for (int off = 64; off > 0; off >>= 1) {
        if (n < off) red[n] = fmaxf(red[n], red[n + off]);
        __syncthreads();
    }
    float mx = red[0];
    __syncthreads();
    float e = __expf(s - mx);
    red[n] = e;
    __syncthreads();
    for (int off = 64; off > 0; off >>= 1) {
        if (n < off) red[n] += red[n + off];
        __syncthreads();
    }
    float sum = red[0];

    out[t] = e / sum;

    if (n < NE) atomicAdd(&importance[n], impS[n]);
}

// ---------------------------------------------------------------------------
// K4: moe_loss from importance (f32 at out[T]).
// ---------------------------------------------------------------------------
__global__ void loss_kernel(const float* __restrict__ importance,
                            float* __restrict__ out) {
    if (threadIdx.x == 0) {
        float mean = 0.f;
        #pragma unroll
        for (int e = 0; e < NE; ++e) mean += importance[e];
        mean *= (1.f / NE);
        float var = 0.f;
        #pragma unroll
        for (int e = 0; e < NE; ++e) {
            float d = importance[e] - mean;
            var += d * d;
        }
        var *= (1.f / NE);
        out[T] = var / (mean * mean + 1e-10f);
    }
}

// ---------------------------------------------------------------------------
extern "C" void kernel_launch(void* const* d_in, const int* in_sizes, int n_in,
                              void* d_out, int out_size, void* d_ws, size_t ws_size,
                              hipStream_t stream) {
    const float* nodes  = (const float*)d_in[0];
    const float* routes = (const float*)d_in[1];
    const float* ninf   = (const float*)d_in[2];
    const float* rmask  = (const float*)d_in[3];
    const float* Wq     = (const float*)d_in[4];
    const float* Wk     = (const float*)d_in[5];
    const float* Wv     = (const float*)d_in[6];
    const float* Wg     = (const float*)d_in[7];
    const float* We     = (const float*)d_in[8];
    const float* be     = (const float*)d_in[9];
    const float* Wfin   = (const float*)d_in[10];

    float* ws = (float*)d_ws;
    float* Wep        = ws + 16;
    float* bpv        = ws + 1040;
    float* importance = ws + 1048;
    float* qbuf       = ws + 4096;
    float* kbuf       = qbuf + (long)T * HD;
    float* vbuf       = kbuf + (long)T * HD;
    float* xcat       = vbuf + (long)T * HD;

    float* out = (float*)d_out;

    prep_kernel<<<NE, 128, 0, stream>>>(We, be, Wfin, Wep, bpv, importance);
    proj_kernel<<<dim3(400, 3), 256, 0, stream>>>(nodes, routes, Wq, Wk, Wv,
                                                  qbuf, kbuf, vbuf);
    attn_kernel<<<dim3(BP, H), 128, 0, stream>>>(qbuf, kbuf, vbuf,
                                                 rmask, ninf, xcat);
    moe_final_kernel<<<BP, 128, 0, stream>>>(xcat, Wg, ninf, Wep, bpv,
                                             importance, out);
    loss_kernel<<<1, 64, 0, stream>>>(importance, out);
}

// Round 12
// 289.670 us; speedup vs baseline: 1.3320x; 1.0601x over previous
//
#include <hip/hip_runtime.h>

constexpr int B  = 8,  P = 50, N = 128, M = 128;
constexpr int EMB = 128, H = 8, D = 16;
constexpr int NE = 8;
constexpr int HD = H * D;        // 128
constexpr int E1 = EMB + 1;      // 129
constexpr int BP = B * P;        // 400
constexpr int T  = BP * N;       // 51200 tokens

// ---------------------------------------------------------------------------
// K0: We'[e][f] = sum_o We[e][f][o]*Wfinal[o]; b'[e] = be[e].Wfinal.
// ---------------------------------------------------------------------------
__global__ void prep_kernel(const float* __restrict__ We,
                            const float* __restrict__ be,
                            const float* __restrict__ Wf,
                            float* __restrict__ Wep, float* __restrict__ bpv,
                            float* __restrict__ importance) {
    const int e = blockIdx.x;
    const int f = threadIdx.x;

    float a = 0.f;
    const long base = ((long)e * HD + f) * E1;
    for (int o = 0; o < E1; ++o) a += We[base + o] * Wf[o];
    Wep[e * HD + f] = a;

    if (f == 0) {
        float b = 0.f;
        for (int o = 0; o < E1; ++o) b += be[(long)e * E1 + o] * Wf[o];
        bpv[e] = b;
    }
    if (e == 0 && f < NE) importance[f] = 0.f;
}

// ---------------------------------------------------------------------------
// K1: q/k/v projections (r7-proven). grid (400, 3), block 256. 128x128 tile,
// 8x8 acc, K-tile 8, ping-pong LDS, one barrier per tile, reg-staged loads.
// ---------------------------------------------------------------------------
__global__ __launch_bounds__(256) void proj_kernel(
    const float* __restrict__ nodes,  // [T][128]
    const float* __restrict__ routes, // [T][129]
    const float* __restrict__ Wq, const float* __restrict__ Wk,
    const float* __restrict__ Wv,
    float* __restrict__ qo, float* __restrict__ ko, float* __restrict__ vo) {
    const int mat = blockIdx.y;
    const float* __restrict__ X = (mat == 0) ? nodes : routes;
    const float* __restrict__ W = (mat == 0) ? Wq : (mat == 1 ? Wk : Wv);
    float* __restrict__ out     = (mat == 0) ? qo : (mat == 1 ? ko : vo);
    const int Kd = (mat == 0) ? EMB : E1;
    const int nit = (Kd + 7) >> 3;

    const int row0 = blockIdx.x * 128;
    const int tid  = threadIdx.x;
    const int tr   = tid >> 4;        // 0..15
    const int tc   = tid & 15;        // 0..15

    __shared__ float XT[2][8][132];   // [buf][k][row], padded
    __shared__ float WS[2][8][132];   // [buf][k][col]

    float acc[8][8];
    #pragma unroll
    for (int i = 0; i < 8; ++i)
        #pragma unroll
        for (int j = 0; j < 8; ++j) acc[i][j] = 0.f;

    float xr[4];
    float4 wr;
    const int xkx = tid & 7, xrr = tid >> 3;          // +i*32 rows
    const int wkx = tid >> 5, wc4 = (tid & 31) * 4;

    {   // prologue: fetch tile 0
        #pragma unroll
        for (int i = 0; i < 4; ++i) {
            int kg = xkx;
            xr[i] = (kg < Kd) ? X[(long)(row0 + xrr + i * 32) * Kd + kg] : 0.f;
        }
        wr = (wkx < Kd) ? *(const float4*)&W[(long)wkx * HD + wc4]
                        : make_float4(0.f, 0.f, 0.f, 0.f);
        #pragma unroll
        for (int i = 0; i < 4; ++i) XT[0][xkx][xrr + i * 32] = xr[i];
        *(float4*)&WS[0][wkx][wc4] = wr;
    }
    __syncthreads();

    for (int it = 0; it < nit; ++it) {
        const int buf = it & 1;
        if (it + 1 < nit) {
            const int kk = (it + 1) * 8;
            #pragma unroll
            for (int i = 0; i < 4; ++i) {
                int kg = kk + xkx;
                xr[i] = (kg < Kd) ? X[(long)(row0 + xrr + i * 32) * Kd + kg] : 0.f;
            }
            int kg = kk + wkx;
            wr = (kg < Kd) ? *(const float4*)&W[(long)kg * HD + wc4]
                           : make_float4(0.f, 0.f, 0.f, 0.f);
        }

        #pragma unroll
        for (int k = 0; k < 8; ++k) {
            float4 xa = *(const float4*)&XT[buf][k][tr * 4];
            float4 xb = *(const float4*)&XT[buf][k][64 + tr * 4];
            float4 wa = *(const float4*)&WS[buf][k][tc * 4];
            float4 wb = *(const float4*)&WS[buf][k][64 + tc * 4];
            float xv[8] = {xa.x, xa.y, xa.z, xa.w, xb.x, xb.y, xb.z, xb.w};
            float wvv[8] = {wa.x, wa.y, wa.z, wa.w, wb.x, wb.y, wb.z, wb.w};
            #pragma unroll
            for (int i = 0; i < 8; ++i)
                #pragma unroll
                for (int j = 0; j < 8; ++j) acc[i][j] += xv[i] * wvv[j];
        }

        if (it + 1 < nit) {
            const int nb = buf ^ 1;
            #pragma unroll
            for (int i = 0; i < 4; ++i) XT[nb][xkx][xrr + i * 32] = xr[i];
            *(float4*)&WS[nb][wkx][wc4] = wr;
        }
        __syncthreads();
    }

    #pragma unroll
    for (int i = 0; i < 8; ++i) {
        int r = row0 + (i < 4 ? 0 : 64) + tr * 4 + (i & 3);
        float4 o0 = make_float4(acc[i][0], acc[i][1], acc[i][2], acc[i][3]);
        float4 o1 = make_float4(acc[i][4], acc[i][5], acc[i][6], acc[i][7]);
        *(float4*)&out[(long)r * HD + tc * 4]      = o0;
        *(float4*)&out[(long)r * HD + 64 + tc * 4] = o1;
    }
}

// ---------------------------------------------------------------------------
// K2: masked attention per (bp, head). grid (BP, 8), block 64 (1 wave).
// r7 structure; only k staged in LDS (8 KB). v streams from global with
// wave-uniform addresses (64-lane broadcast via L1/L2). Staging loop is
// 8 iterations = 512 float4s = all 128 kh rows (r11 bug: was 4).
// ---------------------------------------------------------------------------
__global__ __launch_bounds__(64) void attn_kernel(
    const float* __restrict__ qbuf,   // [T][128]
    const float* __restrict__ kbuf,   // [T][128]
    const float* __restrict__ vbuf,   // [T][128]
    const float* __restrict__ rmask,  // [BP*N][M]
    const float* __restrict__ ninf,   // [BP*N]
    float* __restrict__ xcat) {       // [T][128]
    const int bp  = blockIdx.x;
    const int h   = blockIdx.y;
    const int tid = threadIdx.x;

    __shared__ float kh[M][D];        // 8 KB (k only)

    // stage k: 512 float4s over 8 iterations (fills ALL 128 rows)
    #pragma unroll
    for (int i = 0; i < 8; ++i) {
        int e = tid + i * 64;         // f4 index 0..511
        int r = e >> 2, c4 = (e & 3) * 4;
        *(float4*)&kh[r][c4] = *(const float4*)&kbuf[((long)bp * M + r) * HD + h * D + c4];
    }
    __syncthreads();

    const long t0 = (long)bp * N + tid, t1 = t0 + 64;

    // q rows, 1/sqrt(D)=0.25 folded in
    float qr0[16], qr1[16];
    {
        const float4* q0 = (const float4*)&qbuf[t0 * HD + h * D];
        const float4* q1 = (const float4*)&qbuf[t1 * HD + h * D];
        #pragma unroll
        for (int i = 0; i < 4; ++i) {
            float4 a = q0[i], b = q1[i];
            qr0[i*4+0] = a.x*0.25f; qr0[i*4+1] = a.y*0.25f;
            qr0[i*4+2] = a.z*0.25f; qr0[i*4+3] = a.w*0.25f;
            qr1[i*4+0] = b.x*0.25f; qr1[i*4+1] = b.y*0.25f;
            qr1[i*4+2] = b.z*0.25f; qr1[i*4+3] = b.w*0.25f;
        }
    }

    const float* __restrict__ vbase = vbuf + ((long)bp * M) * HD + h * D;
    const float4* rm0 = (const float4*)&rmask[t0 * M];
    const float4* rm1 = (const float4*)&rmask[t1 * M];

    float sum0 = 0.f, sum1 = 0.f;
    float o0[16], o1[16];
    #pragma unroll
    for (int d = 0; d < 16; ++d) { o0[d] = 0.f; o1[d] = 0.f; }

    for (int mb = 0; mb < 32; ++mb) {          // NOT force-unrolled (VGPR!)
        float4 r0 = rm0[mb], r1 = rm1[mb];
        float r0v[4] = {r0.x, r0.y, r0.z, r0.w};
        float r1v[4] = {r1.x, r1.y, r1.z, r1.w};
        #pragma unroll
        for (int j = 0; j < 4; ++j) {
            const int m = mb * 4 + j;
            const float4* k4 = (const float4*)&kh[m][0];
            const float4* v4 = (const float4*)&vbase[(long)m * HD];  // global, wave-uniform
            float s0 = 0.f, s1 = 0.f;
            #pragma unroll
            for (int q4 = 0; q4 < 4; ++q4) {
                float4 kq = k4[q4];
                s0 += qr0[q4*4+0]*kq.x + qr0[q4*4+1]*kq.y
                    + qr0[q4*4+2]*kq.z + qr0[q4*4+3]*kq.w;
                s1 += qr1[q4*4+0]*kq.x + qr1[q4*4+1]*kq.y
                    + qr1[q4*4+2]*kq.z + qr1[q4*4+3]*kq.w;
            }
            float e0 = __expf(s0 + r0v[j]);
            float e1 = __expf(s1 + r1v[j]);
            sum0 += e0; sum1 += e1;
            #pragma unroll
            for (int q4 = 0; q4 < 4; ++q4) {
                float4 vq = v4[q4];
                o0[q4*4+0] += e0*vq.x; o0[q4*4+1] += e0*vq.y;
                o0[q4*4+2] += e0*vq.z; o0[q4*4+3] += e0*vq.w;
                o1[q4*4+0] += e1*vq.x; o1[q4*4+1] += e1*vq.y;
                o1[q4*4+2] += e1*vq.z; o1[q4*4+3] += e1*vq.w;
            }
        }
    }

    const float inv0 = ((ninf[t0] == 0.f) ? 1.f : 0.f) / sum0;
    const float inv1 = ((ninf[t1] == 0.f) ? 1.f : 0.f) / sum1;
    #pragma unroll
    for (int q4 = 0; q4 < 4; ++q4) {
        float4 w0 = make_float4(o0[q4*4+0]*inv0, o0[q4*4+1]*inv0,
                                o0[q4*4+2]*inv0, o0[q4*4+3]*inv0);
        float4 w1 = make_float4(o1[q4*4+0]*inv1, o1[q4*4+1]*inv1,
                                o1[q4*4+2]*inv1, o1[q4*4+3]*inv1);
        *(float4*)&xcat[t0 * HD + h * D + q4 * 4] = w0;
        *(float4*)&xcat[t1 * HD + h * D + q4 * 4] = w1;
    }
}

// ---------------------------------------------------------------------------
// K3: MoE gating (top-2) + collapsed expert scoring + final softmax.
// grid BP, block 128 (thread = token n). (r5/r7-proven version)
// ---------------------------------------------------------------------------
__global__ __launch_bounds__(128) void moe_final_kernel(
    const float* __restrict__ xcat, const float* __restrict__ Wg,
    const float* __restrict__ ninf, const float* __restrict__ Wep,
    const float* __restrict__ bpv, float* __restrict__ importance,
    float* __restrict__ out) {
    __shared__ float WgS[EMB][NE];   // 4 KB
    __shared__ float WeS[NE][132];   // padded
    __shared__ float red[N];
    __shared__ float impS[NE];

    const int bp = blockIdx.x;
    const int n  = threadIdx.x;

    #pragma unroll
    for (int i = 0; i < 2; ++i) {
        int e = n + i * 128;
        int r = e >> 1, c4 = (e & 1) * 4;
        *(float4*)&WgS[r][c4] = *(const float4*)&Wg[(long)r * NE + c4];
    }
    #pragma unroll
    for (int i = 0; i < 2; ++i) {
        int idx = n + i * 128;
        int r = idx >> 5, c = (idx & 31) * 4;
        *(float4*)&WeS[r][c] = *(const float4*)&Wep[(long)r * HD + c];
    }
    if (n < NE) impS[n] = 0.f;
    __syncthreads();

    const long t = (long)bp * N + n;
    const float4* row4 = (const float4*)&xcat[t * HD];

    float gl[NE];
    #pragma unroll
    for (int e = 0; e < NE; ++e) gl[e] = 0.f;
    for (int fb = 0; fb < 32; ++fb) {
        float4 xv = row4[fb];
        float x4[4] = {xv.x, xv.y, xv.z, xv.w};
        #pragma unroll
        for (int j = 0; j < 4; ++j)
            #pragma unroll
            for (int e = 0; e < NE; ++e) gl[e] += x4[j] * WgS[fb * 4 + j][e];
    }

    int e0 = 0; float v0 = gl[0];
    #pragma unroll
    for (int e = 1; e < NE; ++e) if (gl[e] > v0) { v0 = gl[e]; e0 = e; }
    int e1 = -1; float v1 = -3.4e38f;
    #pragma unroll
    for (int e = 0; e < NE; ++e) if (e != e0 && gl[e] > v1) { v1 = gl[e]; e1 = e; }
    float ex = __expf(v1 - v0);
    float g0 = 1.f / (1.f + ex);
    float g1 = ex / (1.f + ex);

    atomicAdd(&impS[e0], g0);
    atomicAdd(&impS[e1], g1);

    float s = g0 * bpv[e0] + g1 * bpv[e1];
    for (int fb = 0; fb < 32; ++fb) {
        float4 xv = row4[fb];
        float x4[4] = {xv.x, xv.y, xv.z, xv.w};
        #pragma unroll
        for (int j = 0; j < 4; ++j) {
            int f = fb * 4 + j;
            s += x4[j] * (g0 * WeS[e0][f] + g1 * WeS[e1][f]);
        }
    }
    s = 10.f * tanhf(s) + ninf[t];

    red[n] = s;
    __syncthreads();
    for (int off = 64; off > 0; off >>= 1) {
        if (n < off) red[n] = fmaxf(red[n], red[n + off]);
        __syncthreads();
    }
    float mx = red[0];
    __syncthreads();
    float e = __expf(s - mx);
    red[n] = e;
    __syncthreads();
    for (int off = 64; off > 0; off >>= 1) {
        if (n < off) red[n] += red[n + off];
        __syncthreads();
    }
    float sum = red[0];

    out[t] = e / sum;

    if (n < NE) atomicAdd(&importance[n], impS[n]);
}

// ---------------------------------------------------------------------------
// K4: moe_loss from importance (f32 at out[T]).
// ---------------------------------------------------------------------------
__global__ void loss_kernel(const float* __restrict__ importance,
                            float* __restrict__ out) {
    if (threadIdx.x == 0) {
        float mean = 0.f;
        #pragma unroll
        for (int e = 0; e < NE; ++e) mean += importance[e];
        mean *= (1.f / NE);
        float var = 0.f;
        #pragma unroll
        for (int e = 0; e < NE; ++e) {
            float d = importance[e] - mean;
            var += d * d;
        }
        var *= (1.f / NE);
        out[T] = var / (mean * mean + 1e-10f);
    }
}

// ---------------------------------------------------------------------------
extern "C" void kernel_launch(void* const* d_in, const int* in_sizes, int n_in,
                              void* d_out, int out_size, void* d_ws, size_t ws_size,
                              hipStream_t stream) {
    const float* nodes  = (const float*)d_in[0];
    const float* routes = (const float*)d_in[1];
    const float* ninf   = (const float*)d_in[2];
    const float* rmask  = (const float*)d_in[3];
    const float* Wq     = (const float*)d_in[4];
    const float* Wk     = (const float*)d_in[5];
    const float* Wv     = (const float*)d_in[6];
    const float* Wg     = (const float*)d_in[7];
    const float* We     = (const float*)d_in[8];
    const float* be     = (const float*)d_in[9];
    const float* Wfin   = (const float*)d_in[10];

    float* ws = (float*)d_ws;
    float* Wep        = ws + 16;
    float* bpv        = ws + 1040;
    float* importance = ws + 1048;
    float* qbuf       = ws + 4096;
    float* kbuf       = qbuf + (long)T * HD;
    float* vbuf       = kbuf + (long)T * HD;
    float* xcat       = vbuf + (long)T * HD;

    float* out = (float*)d_out;

    prep_kernel<<<NE, 128, 0, stream>>>(We, be, Wfin, Wep, bpv, importance);
    proj_kernel<<<dim3(400, 3), 256, 0, stream>>>(nodes, routes, Wq, Wk, Wv,
                                                  qbuf, kbuf, vbuf);
    attn_kernel<<<dim3(BP, H), 64, 0, stream>>>(qbuf, kbuf, vbuf,
                                                rmask, ninf, xcat);
    moe_final_kernel<<<BP, 128, 0, stream>>>(xcat, Wg, ninf, Wep, bpv,
                                             importance, out);
    loss_kernel<<<1, 64, 0, stream>>>(importance, out);
}